// Round 6
// baseline (71.408 us; speedup 1.0000x reference)
//
#include <hip/hip_runtime.h>

#define NB 8
#define SL 128
#define HD 768

// Kernel 1: one block per (b,i). hidden + keyemb gather (ballot-rank pack).
__global__ __launch_bounds__(256) void k_pack_gather(
    const float* __restrict__ seq,
    const float* __restrict__ W_key,
    const int* __restrict__ valid,
    const int* __restrict__ kvidx,
    const int* __restrict__ aspect,
    float* __restrict__ hidden,
    float* __restrict__ keyemb) {
  int blk = blockIdx.x;
  int b = blk & 7;
  int i = blk >> 3;
  int bq = b * SL + i;
  int tid = threadIdx.x;
  int lane = tid & 63, wv = tid >> 6;

  __shared__ int s_wcnt[4];
  __shared__ int s_src;

  int v = (tid < SL) ? (valid[b * SL + tid] != 0) : 0;
  unsigned long long m = __ballot(v);
  if (lane == 0) s_wcnt[wv] = __popcll(m);
  if (tid == 0) s_src = SL;  // sentinel
  __syncthreads();
  int count = s_wcnt[0] + s_wcnt[1];
  if (v) {
    int rank = __popcll(m & ((1ull << lane) - 1ull)) + (wv == 1 ? s_wcnt[0] : 0);
    if (rank == i) s_src = tid;
  }
  __syncthreads();
  int src = s_src;

  if (tid < HD / 4) {  // 192 threads, one float4 each
    float4 hv = make_float4(0.f, 0.f, 0.f, 0.f);
    if (i < count && src < SL) {
      float asp = (float)aspect[b * SL + i];
      const float4* srow = (const float4*)(seq + ((size_t)(b * SL + src)) * HD);
      float4 s = srow[tid];
      hv = make_float4(s.x * asp, s.y * asp, s.z * asp, s.w * asp);
    }
    ((float4*)(hidden + (size_t)bq * HD))[tid] = hv;

    int id = kvidx[b * SL + i];
    float4 kv = make_float4(0.f, 0.f, 0.f, 0.f);
    if (id != 0) {
      kv = ((const float4*)(W_key + (size_t)id * HD))[tid];
    }
    ((float4*)(keyemb + (size_t)bq * HD))[tid] = kv;
  }
}

// Kernel 2 (fused, QT=4): block = (b, 4-q tile), 512 threads / 8 waves.
// QK with hidden in registers (amortizes key-row loads 4x) -> masked softmax
// (4 rows in parallel) -> compacted register-pipelined gather (2 waves/q).
// blockIdx % 8 == b pins each batch to one XCD (keyemb panel L2-local).
__global__ __launch_bounds__(512) void k_attend(
    const float* __restrict__ hidden,
    const float* __restrict__ keyemb,
    const int* __restrict__ features,
    const int* __restrict__ pos,
    const float* __restrict__ W_val,
    float* __restrict__ o) {
  int blk = blockIdx.x;
  int b = blk & 7;
  int q0 = (blk >> 3) * 4;
  int bq0 = b * SL + q0;
  int tid = threadIdx.x;
  int wave = tid >> 6, lane = tid & 63;

  __shared__ float s_p[4][SL];
  __shared__ int s_f[4][SL];
  __shared__ float s_pc[4][SL];
  __shared__ int s_fc[4][SL];
  __shared__ float s_o[8][HD];
  __shared__ float s_sum[4];
  __shared__ int s_cnt[8];
  __shared__ int s_m[4];

  // hidden rows q0..q0+3 into registers (per wave; each wave needs all 4)
  float4 hreg[4][3];
#pragma unroll
  for (int q = 0; q < 4; ++q) {
    const float4* hr = (const float4*)(hidden + (size_t)(bq0 + q) * HD);
#pragma unroll
    for (int j = 0; j < 3; ++j) hreg[q][j] = hr[lane + 64 * j];
  }
  {  // features for 4 rows
    int q = tid >> 7, kk = tid & 127;
    s_f[q][kk] = features[((size_t)(bq0 + q)) * SL + kk];
  }

  const float rscale = 0.03608439182435161f;  // 1/sqrt(768)
  for (int k = wave; k < SL; k += 8) {
    const float4* kr4 = (const float4*)(keyemb + ((size_t)(b * SL + k)) * HD);
    float4 kv0 = kr4[lane], kv1 = kr4[lane + 64], kv2 = kr4[lane + 128];
#pragma unroll
    for (int q = 0; q < 4; ++q) {
      float part = kv0.x * hreg[q][0].x + kv0.y * hreg[q][0].y +
                   kv0.z * hreg[q][0].z + kv0.w * hreg[q][0].w +
                   kv1.x * hreg[q][1].x + kv1.y * hreg[q][1].y +
                   kv1.z * hreg[q][1].z + kv1.w * hreg[q][1].w +
                   kv2.x * hreg[q][2].x + kv2.y * hreg[q][2].y +
                   kv2.z * hreg[q][2].z + kv2.w * hreg[q][2].w;
#pragma unroll
      for (int off = 32; off; off >>= 1) part += __shfl_xor(part, off);
      if (lane == 0) s_p[q][k] = part * rscale;
    }
  }
  __syncthreads();
  {  // mask + exp, 4 rows at once
    int q = tid >> 7, kk = tid & 127;
    float d = (pos[((size_t)(bq0 + q)) * SL + kk] != 0) ? expf(s_p[q][kk]) : 0.f;
    s_p[q][kk] = d;
  }
  __syncthreads();
  if (wave < 4) {  // wave q reduces row q's denominator
    float part = s_p[wave][lane] + s_p[wave][lane + 64];
#pragma unroll
    for (int off = 32; off; off >>= 1) part += __shfl_xor(part, off);
    if (lane == 0) s_sum[wave] = part + 1e-10f;
  }
  __syncthreads();

  // compact all 4 rows at once: wave w covers row q=w>>1, half w&1
  {
    int q = tid >> 7, kk = tid & 127;
    float pv = s_p[q][kk] / s_sum[q];
    int fv = s_f[q][kk];
    int keep = (pv != 0.f) && (fv != 0);
    unsigned long long km = __ballot(keep);
    if (lane == 0) s_cnt[wave] = __popcll(km);
    __syncthreads();
    if (keep) {
      int rank = __popcll(km & ((1ull << lane) - 1ull)) +
                 ((wave & 1) ? s_cnt[wave - 1] : 0);
      s_pc[q][rank] = pv;
      s_fc[q][rank] = fv;
    }
    if (tid < 4) s_m[tid] = s_cnt[2 * tid] + s_cnt[2 * tid + 1];
    __syncthreads();
  }

  // gather: wave w -> row q=w&3, slice sl=w>>2; entries e = sl + 2*i.
  int q = wave & 3, sl = wave >> 2;
  int mm = s_m[q];
  int niter = (mm > sl) ? ((mm - sl + 1) >> 1) : 0;
  float myp = 0.f;
  int myf = 0;
  {
    int el = sl + 2 * lane;
    if (el < mm) { myp = s_pc[q][el]; myf = s_fc[q][el]; }
  }
  float4 a0 = make_float4(0.f, 0.f, 0.f, 0.f);
  float4 a1 = a0, a2 = a0;
  float4 v0, v1, v2;
  float pk = 0.f;
  if (niter > 0) {
    pk = __shfl(myp, 0);
    int f = __shfl(myf, 0);
    const float4* vr = (const float4*)(W_val + (size_t)f * HD);
    v0 = vr[lane]; v1 = vr[lane + 64]; v2 = vr[lane + 128];
  }
  for (int j = 1; j < niter; ++j) {
    float pkn = __shfl(myp, j);
    int f = __shfl(myf, j);
    const float4* vr = (const float4*)(W_val + (size_t)f * HD);
    float4 n0 = vr[lane], n1 = vr[lane + 64], n2 = vr[lane + 128];
    a0.x += pk * v0.x; a0.y += pk * v0.y; a0.z += pk * v0.z; a0.w += pk * v0.w;
    a1.x += pk * v1.x; a1.y += pk * v1.y; a1.z += pk * v1.z; a1.w += pk * v1.w;
    a2.x += pk * v2.x; a2.y += pk * v2.y; a2.z += pk * v2.z; a2.w += pk * v2.w;
    v0 = n0; v1 = n1; v2 = n2; pk = pkn;
  }
  if (niter > 0) {
    a0.x += pk * v0.x; a0.y += pk * v0.y; a0.z += pk * v0.z; a0.w += pk * v0.w;
    a1.x += pk * v1.x; a1.y += pk * v1.y; a1.z += pk * v1.z; a1.w += pk * v1.w;
    a2.x += pk * v2.x; a2.y += pk * v2.y; a2.z += pk * v2.z; a2.w += pk * v2.w;
  }
  ((float4*)s_o[wave])[lane] = a0;
  ((float4*)s_o[wave])[lane + 64] = a1;
  ((float4*)s_o[wave])[lane + 128] = a2;
  __syncthreads();

  // combine 2 slices per row, write 4 o-rows
#pragma unroll
  for (int it = 0; it < 6; ++it) {
    int idx = tid + 512 * it;
    int qq = idx / HD, h = idx - qq * HD;
    o[((size_t)(bq0 + qq)) * HD + h] = s_o[qq][h] + s_o[4 + qq][h];
  }
}

// Kernel 3: column mean with !=0 count. grid NB*6; 512 thr, 4 q-sub-slices.
__global__ __launch_bounds__(512) void k_avg(
    const float* __restrict__ o, float* __restrict__ avg) {
  int b = blockIdx.x / 6, c = blockIdx.x % 6;
  int tid = threadIdx.x;
  int hc = tid & 127;
  int h = c * 128 + hc;
  int sub = tid >> 7;  // 0..3, each sums 32 q's
  __shared__ float s_sum[4][128];
  __shared__ int s_cnt[4][128];
  float sum = 0.f;
  int cnt = 0;
#pragma unroll 8
  for (int q = sub * 32; q < (sub + 1) * 32; ++q) {
    float v = o[((size_t)(b * SL + q)) * HD + h];
    sum += v;
    cnt += (v != 0.f) ? 1 : 0;
  }
  s_sum[sub][hc] = sum;
  s_cnt[sub][hc] = cnt;
  __syncthreads();
  if (tid < 128) {
    float t = (s_sum[0][tid] + s_sum[1][tid]) + (s_sum[2][tid] + s_sum[3][tid]);
    int cc = (s_cnt[0][tid] + s_cnt[1][tid]) + (s_cnt[2][tid] + s_cnt[3][tid]);
    avg[(size_t)b * HD + c * 128 + tid] = t / (float)cc;  // IEEE inf/nan if cc==0
  }
}

// Kernel 4: logits = [pooled, avg] @ W_dense^T + b_dense
__global__ __launch_bounds__(192) void k_dense(
    const float* __restrict__ pooled,
    const float* __restrict__ avg,
    const float* __restrict__ W_dense,
    const float* __restrict__ b_dense,
    float* __restrict__ out) {
  int b = blockIdx.x;
  int tid = threadIdx.x;
  int n = tid >> 6, lane = tid & 63;
  float part = 0.f;
  for (int j = lane; j < HD; j += 64)
    part += pooled[(size_t)b * HD + j] * W_dense[(size_t)n * (2 * HD) + j];
  for (int j = lane; j < HD; j += 64)
    part += avg[(size_t)b * HD + j] * W_dense[(size_t)n * (2 * HD) + HD + j];
#pragma unroll
  for (int off = 32; off; off >>= 1) part += __shfl_xor(part, off);
  if (lane == 0) out[b * 3 + n] = part + b_dense[n];
}

extern "C" void kernel_launch(void* const* d_in, const int* in_sizes, int n_in,
                              void* d_out, int out_size, void* d_ws, size_t ws_size,
                              hipStream_t stream) {
  const float* seq     = (const float*)d_in[0];
  const float* pooled  = (const float*)d_in[1];
  const float* W_key   = (const float*)d_in[2];
  const float* W_val   = (const float*)d_in[3];
  const float* W_dense = (const float*)d_in[4];
  const float* b_dense = (const float*)d_in[5];
  const int* valid     = (const int*)d_in[6];
  const int* kvidx     = (const int*)d_in[7];
  const int* features  = (const int*)d_in[8];
  const int* pos       = (const int*)d_in[9];
  const int* aspect    = (const int*)d_in[10];
  float* out = (float*)d_out;

  float* hidden = (float*)d_ws;                       // [B,L,H]
  float* keyemb = hidden + (size_t)NB * SL * HD;      // [B,L,H]
  float* o      = keyemb + (size_t)NB * SL * HD;      // [B,L,H]
  float* avg    = o + (size_t)NB * SL * HD;           // [B,H]

  k_pack_gather<<<NB * SL, 256, 0, stream>>>(seq, W_key, valid, kvidx, aspect, hidden, keyemb);
  k_attend<<<NB * SL / 4, 512, 0, stream>>>(hidden, keyemb, features, pos, W_val, o);
  k_avg<<<NB * 6, 512, 0, stream>>>(o, avg);
  k_dense<<<NB, 192, 0, stream>>>(pooled, avg, W_dense, b_dense, out);
}

// Round 7
// 62.621 us; speedup vs baseline: 1.1403x; 1.1403x over previous
//
#include <hip/hip_runtime.h>

#define NB 8
#define SL 128
#define HD 768

__device__ __forceinline__ float bf_lo(unsigned int u) {
  return __uint_as_float(u << 16);
}
__device__ __forceinline__ float bf_hi(unsigned int u) {
  return __uint_as_float(u & 0xffff0000u);
}
__device__ __forceinline__ unsigned short f2bf(float x) {  // RNE
  unsigned int b = __float_as_uint(x);
  b += 0x7fffu + ((b >> 16) & 1u);
  return (unsigned short)(b >> 16);
}

// Kernel 1: one block per (b,i). hidden (f32) + keyemb (bf16) gather.
__global__ __launch_bounds__(256) void k_pack_gather(
    const float* __restrict__ seq,
    const float* __restrict__ W_key,
    const int* __restrict__ valid,
    const int* __restrict__ kvidx,
    const int* __restrict__ aspect,
    float* __restrict__ hidden,
    unsigned short* __restrict__ keyemb) {
  int blk = blockIdx.x;
  int b = blk & 7;
  int i = blk >> 3;
  int bq = b * SL + i;
  int tid = threadIdx.x;
  int lane = tid & 63, wv = tid >> 6;

  __shared__ int s_wcnt[4];
  __shared__ int s_src;

  int v = (tid < SL) ? (valid[b * SL + tid] != 0) : 0;
  unsigned long long m = __ballot(v);
  if (lane == 0) s_wcnt[wv] = __popcll(m);
  if (tid == 0) s_src = SL;  // sentinel
  __syncthreads();
  int count = s_wcnt[0] + s_wcnt[1];
  if (v) {
    int rank = __popcll(m & ((1ull << lane) - 1ull)) + (wv == 1 ? s_wcnt[0] : 0);
    if (rank == i) s_src = tid;
  }
  __syncthreads();
  int src = s_src;

  if (tid < HD / 4) {  // 192 threads, one float4 / ushort4 each
    float4 hv = make_float4(0.f, 0.f, 0.f, 0.f);
    if (i < count && src < SL) {
      float asp = (float)aspect[b * SL + i];
      const float4* srow = (const float4*)(seq + ((size_t)(b * SL + src)) * HD);
      float4 s = srow[tid];
      hv = make_float4(s.x * asp, s.y * asp, s.z * asp, s.w * asp);
    }
    ((float4*)(hidden + (size_t)bq * HD))[tid] = hv;

    int id = kvidx[b * SL + i];
    ushort4 kb = make_ushort4(0, 0, 0, 0);
    if (id != 0) {
      float4 kv = ((const float4*)(W_key + (size_t)id * HD))[tid];
      kb = make_ushort4(f2bf(kv.x), f2bf(kv.y), f2bf(kv.z), f2bf(kv.w));
    }
    ((ushort4*)(keyemb + (size_t)bq * HD))[tid] = kb;
  }
}

// Kernel 2 (fused, R5 structure): per (b,q) block, 512 threads / 8 waves.
// QK (bf16 keys, hidden in regs) -> masked softmax -> compacted gather with
// 2 entries/wave/iter (niter ~4, 6 independent float4 loads per step).
// blockIdx % 8 == b pins each batch to one XCD (keyemb panel L2-local).
__global__ __launch_bounds__(512) void k_attend(
    const float* __restrict__ hidden,
    const unsigned short* __restrict__ keyemb,
    const int* __restrict__ features,
    const int* __restrict__ pos,
    const float* __restrict__ W_val,
    float* __restrict__ o) {
  int blk = blockIdx.x;
  int b = blk & 7;
  int q = blk >> 3;
  int bq = b * SL + q;
  int tid = threadIdx.x;
  int wave = tid >> 6, lane = tid & 63;

  __shared__ float s_p[SL];
  __shared__ int s_f[SL];
  __shared__ float s_pc[SL];
  __shared__ int s_fc[SL];
  __shared__ float s_o[8][HD];
  __shared__ float s_sum;
  __shared__ int s_cnt2[2];
  __shared__ int s_m;

  // hidden row into registers (each wave holds the full row, float4 layout)
  float4 hreg[3];
  {
    const float4* h4 = (const float4*)(hidden + (size_t)bq * HD);
#pragma unroll
    for (int j = 0; j < 3; ++j) hreg[j] = h4[lane + 64 * j];
  }
  if (tid < SL) s_f[tid] = features[(size_t)bq * SL + tid];

  const float rscale = 0.03608439182435161f;  // 1/sqrt(768)
  for (int k = wave; k < SL; k += 8) {
    const uint2* kr = (const uint2*)(keyemb + ((size_t)(b * SL + k)) * HD);
    float part = 0.f;
#pragma unroll
    for (int j = 0; j < 3; ++j) {
      uint2 kv = kr[lane + 64 * j];  // 4 bf16 elems
      float4 h = hreg[j];
      part += bf_lo(kv.x) * h.x + bf_hi(kv.x) * h.y +
              bf_lo(kv.y) * h.z + bf_hi(kv.y) * h.w;
    }
#pragma unroll
    for (int off = 32; off; off >>= 1) part += __shfl_xor(part, off);
    if (lane == 0) s_p[k] = part * rscale;
  }
  __syncthreads();
  if (tid < SL) {
    float d = (pos[(size_t)bq * SL + tid] != 0) ? expf(s_p[tid]) : 0.f;
    s_p[tid] = d;
  }
  __syncthreads();
  if (tid < 64) {  // wave 0 tree-reduces the denominator
    float part = s_p[tid] + s_p[tid + 64];
#pragma unroll
    for (int off = 32; off; off >>= 1) part += __shfl_xor(part, off);
    if (tid == 0) s_sum = part + 1e-10f;
  }
  __syncthreads();

  // compact surviving (p, f) pairs
  int keep = 0;
  float pv = 0.f;
  int fv = 0;
  if (tid < SL) {
    pv = s_p[tid] / s_sum;
    fv = s_f[tid];
    keep = (pv != 0.f) && (fv != 0);
  }
  unsigned long long km = __ballot(keep);
  if (lane == 0 && wave < 2) s_cnt2[wave] = __popcll(km);
  __syncthreads();
  if (keep) {
    int rank = __popcll(km & ((1ull << lane) - 1ull)) + (wave == 1 ? s_cnt2[0] : 0);
    s_pc[rank] = pv;
    s_fc[rank] = fv;
  }
  if (tid == 0) s_m = s_cnt2[0] + s_cnt2[1];
  __syncthreads();
  int mm = s_m;

  // Gather: wave w handles entries e = 2w + 16*i and 2w+1 + 16*i.
  // niter uniform across waves; tail entries have pk == 0 (harmless row-0 load).
  int niter = (mm + 15) >> 4;
  float myp = 0.f;
  int myf = 0;
  {
    int el = 2 * wave + 16 * (lane >> 1) + (lane & 1);
    if (lane < 16 && el < mm) { myp = s_pc[el]; myf = s_fc[el]; }
  }
  float4 a0 = make_float4(0.f, 0.f, 0.f, 0.f);
  float4 a1 = a0, a2 = a0;
  for (int j = 0; j < niter; ++j) {
    float pk0 = __shfl(myp, 2 * j);
    int f0 = __shfl(myf, 2 * j);
    float pk1 = __shfl(myp, 2 * j + 1);
    int f1 = __shfl(myf, 2 * j + 1);
    const float4* vr0 = (const float4*)(W_val + (size_t)f0 * HD);
    const float4* vr1 = (const float4*)(W_val + (size_t)f1 * HD);
    float4 x0 = vr0[lane], x1 = vr0[lane + 64], x2 = vr0[lane + 128];
    float4 y0 = vr1[lane], y1 = vr1[lane + 64], y2 = vr1[lane + 128];
    a0.x += pk0 * x0.x; a0.y += pk0 * x0.y; a0.z += pk0 * x0.z; a0.w += pk0 * x0.w;
    a1.x += pk0 * x1.x; a1.y += pk0 * x1.y; a1.z += pk0 * x1.z; a1.w += pk0 * x1.w;
    a2.x += pk0 * x2.x; a2.y += pk0 * x2.y; a2.z += pk0 * x2.z; a2.w += pk0 * x2.w;
    a0.x += pk1 * y0.x; a0.y += pk1 * y0.y; a0.z += pk1 * y0.z; a0.w += pk1 * y0.w;
    a1.x += pk1 * y1.x; a1.y += pk1 * y1.y; a1.z += pk1 * y1.z; a1.w += pk1 * y1.w;
    a2.x += pk1 * y2.x; a2.y += pk1 * y2.y; a2.z += pk1 * y2.z; a2.w += pk1 * y2.w;
  }
  ((float4*)s_o[wave])[lane] = a0;
  ((float4*)s_o[wave])[lane + 64] = a1;
  ((float4*)s_o[wave])[lane + 128] = a2;
  __syncthreads();

  float* orow = o + (size_t)bq * HD;
  for (int h = tid; h < HD; h += 512) {
    float s = 0.f;
#pragma unroll
    for (int w = 0; w < 8; ++w) s += s_o[w][h];
    orow[h] = s;
  }
}

// Kernel 3: column mean with !=0 count. grid NB*6; 512 thr, 4 q-sub-slices.
__global__ __launch_bounds__(512) void k_avg(
    const float* __restrict__ o, float* __restrict__ avg) {
  int b = blockIdx.x / 6, c = blockIdx.x % 6;
  int tid = threadIdx.x;
  int hc = tid & 127;
  int h = c * 128 + hc;
  int sub = tid >> 7;  // 0..3, each sums 32 q's
  __shared__ float s_sum[4][128];
  __shared__ int s_cnt[4][128];
  float sum = 0.f;
  int cnt = 0;
#pragma unroll 8
  for (int q = sub * 32; q < (sub + 1) * 32; ++q) {
    float v = o[((size_t)(b * SL + q)) * HD + h];
    sum += v;
    cnt += (v != 0.f) ? 1 : 0;
  }
  s_sum[sub][hc] = sum;
  s_cnt[sub][hc] = cnt;
  __syncthreads();
  if (tid < 128) {
    float t = (s_sum[0][tid] + s_sum[1][tid]) + (s_sum[2][tid] + s_sum[3][tid]);
    int cc = (s_cnt[0][tid] + s_cnt[1][tid]) + (s_cnt[2][tid] + s_cnt[3][tid]);
    avg[(size_t)b * HD + c * 128 + tid] = t / (float)cc;  // IEEE inf/nan if cc==0
  }
}

// Kernel 4: logits = [pooled, avg] @ W_dense^T + b_dense
__global__ __launch_bounds__(192) void k_dense(
    const float* __restrict__ pooled,
    const float* __restrict__ avg,
    const float* __restrict__ W_dense,
    const float* __restrict__ b_dense,
    float* __restrict__ out) {
  int b = blockIdx.x;
  int tid = threadIdx.x;
  int n = tid >> 6, lane = tid & 63;
  float part = 0.f;
  for (int j = lane; j < HD; j += 64)
    part += pooled[(size_t)b * HD + j] * W_dense[(size_t)n * (2 * HD) + j];
  for (int j = lane; j < HD; j += 64)
    part += avg[(size_t)b * HD + j] * W_dense[(size_t)n * (2 * HD) + HD + j];
#pragma unroll
  for (int off = 32; off; off >>= 1) part += __shfl_xor(part, off);
  if (lane == 0) out[b * 3 + n] = part + b_dense[n];
}

extern "C" void kernel_launch(void* const* d_in, const int* in_sizes, int n_in,
                              void* d_out, int out_size, void* d_ws, size_t ws_size,
                              hipStream_t stream) {
  const float* seq     = (const float*)d_in[0];
  const float* pooled  = (const float*)d_in[1];
  const float* W_key   = (const float*)d_in[2];
  const float* W_val   = (const float*)d_in[3];
  const float* W_dense = (const float*)d_in[4];
  const float* b_dense = (const float*)d_in[5];
  const int* valid     = (const int*)d_in[6];
  const int* kvidx     = (const int*)d_in[7];
  const int* features  = (const int*)d_in[8];
  const int* pos       = (const int*)d_in[9];
  const int* aspect    = (const int*)d_in[10];
  float* out = (float*)d_out;

  float* hidden = (float*)d_ws;                              // [B,L,H] f32
  unsigned short* keyemb = (unsigned short*)(hidden + (size_t)NB * SL * HD);  // [B,L,H] bf16
  float* o = (float*)(keyemb + (size_t)NB * SL * HD);        // [B,L,H] f32
  float* avg = o + (size_t)NB * SL * HD;                     // [B,H]

  k_pack_gather<<<NB * SL, 256, 0, stream>>>(seq, W_key, valid, kvidx, aspect, hidden, keyemb);
  k_attend<<<NB * SL, 512, 0, stream>>>(hidden, keyemb, features, pos, W_val, o);
  k_avg<<<NB * 6, 512, 0, stream>>>(o, avg);
  k_dense<<<NB, 192, 0, stream>>>(pooled, avg, W_dense, b_dense, out);
}

// Round 8
// 57.021 us; speedup vs baseline: 1.2523x; 1.0982x over previous
//
#include <hip/hip_runtime.h>

#define NB 8
#define SL 128
#define HD 768

__device__ __forceinline__ float bf_lo(unsigned int u) {
  return __uint_as_float(u << 16);
}
__device__ __forceinline__ float bf_hi(unsigned int u) {
  return __uint_as_float(u & 0xffff0000u);
}
__device__ __forceinline__ unsigned short f2bf(float x) {  // RNE
  unsigned int b = __float_as_uint(x);
  b += 0x7fffu + ((b >> 16) & 1u);
  return (unsigned short)(b >> 16);
}

// Kernel 1: blocks [0,1024): per-(b,i) pack -> hidden (f32) + keyemb (bf16).
// blocks [1024,4096): stream-convert W_val (16384x768 f32) -> bf16.
__global__ __launch_bounds__(256) void k_prep(
    const float* __restrict__ seq,
    const float* __restrict__ W_key,
    const float* __restrict__ W_val,
    const int* __restrict__ valid,
    const int* __restrict__ kvidx,
    const int* __restrict__ aspect,
    float* __restrict__ hidden,
    unsigned short* __restrict__ keyemb,
    unsigned short* __restrict__ wv16) {
  int blk = blockIdx.x;
  int tid = threadIdx.x;

  if (blk >= NB * SL) {
    // W_val conversion: 3072 blocks x 256 thr x 4 float4 = 12.58M elems
    int cb = blk - NB * SL;
    const float4* src = (const float4*)W_val;
    ushort4* dst = (ushort4*)wv16;
    int base = cb * 1024 + tid;
#pragma unroll
    for (int it = 0; it < 4; ++it) {
      float4 v = src[base + 256 * it];
      dst[base + 256 * it] =
          make_ushort4(f2bf(v.x), f2bf(v.y), f2bf(v.z), f2bf(v.w));
    }
    return;
  }

  int b = blk & 7;
  int i = blk >> 3;
  int bq = b * SL + i;
  int lane = tid & 63, wv = tid >> 6;

  __shared__ int s_wcnt[4];
  __shared__ int s_src;

  int v = (tid < SL) ? (valid[b * SL + tid] != 0) : 0;
  unsigned long long m = __ballot(v);
  if (lane == 0) s_wcnt[wv] = __popcll(m);
  if (tid == 0) s_src = SL;  // sentinel
  __syncthreads();
  int count = s_wcnt[0] + s_wcnt[1];
  if (v) {
    int rank = __popcll(m & ((1ull << lane) - 1ull)) + (wv == 1 ? s_wcnt[0] : 0);
    if (rank == i) s_src = tid;
  }
  __syncthreads();
  int src = s_src;

  if (tid < HD / 4) {  // 192 threads, one float4 / ushort4 each
    float4 hv = make_float4(0.f, 0.f, 0.f, 0.f);
    if (i < count && src < SL) {
      float asp = (float)aspect[b * SL + i];
      const float4* srow = (const float4*)(seq + ((size_t)(b * SL + src)) * HD);
      float4 s = srow[tid];
      hv = make_float4(s.x * asp, s.y * asp, s.z * asp, s.w * asp);
    }
    ((float4*)(hidden + (size_t)bq * HD))[tid] = hv;

    int id = kvidx[b * SL + i];
    ushort4 kb = make_ushort4(0, 0, 0, 0);
    if (id != 0) {
      float4 kv = ((const float4*)(W_key + (size_t)id * HD))[tid];
      kb = make_ushort4(f2bf(kv.x), f2bf(kv.y), f2bf(kv.z), f2bf(kv.w));
    }
    ((ushort4*)(keyemb + (size_t)bq * HD))[tid] = kb;
  }
}

// Kernel 2 (fused): per (b,q) block, 512 threads / 8 waves.
// QK (bf16 keys, hidden in regs) -> masked softmax -> compacted gather of
// bf16 W_val rows, 2 entries/wave/iter (6 independent 8B loads per step).
// blockIdx % 8 == b pins each batch to one XCD (keyemb panel L2-local).
__global__ __launch_bounds__(512) void k_attend(
    const float* __restrict__ hidden,
    const unsigned short* __restrict__ keyemb,
    const int* __restrict__ features,
    const int* __restrict__ pos,
    const unsigned short* __restrict__ wv16,
    float* __restrict__ o) {
  int blk = blockIdx.x;
  int b = blk & 7;
  int q = blk >> 3;
  int bq = b * SL + q;
  int tid = threadIdx.x;
  int wave = tid >> 6, lane = tid & 63;

  __shared__ float s_p[SL];
  __shared__ int s_f[SL];
  __shared__ float s_pc[SL];
  __shared__ int s_fc[SL];
  __shared__ float s_o[8][HD];
  __shared__ float s_sum;
  __shared__ int s_cnt2[2];
  __shared__ int s_m;

  // hidden row into registers (each wave holds the full row, float4 layout)
  float4 hreg[3];
  {
    const float4* h4 = (const float4*)(hidden + (size_t)bq * HD);
#pragma unroll
    for (int j = 0; j < 3; ++j) hreg[j] = h4[lane + 64 * j];
  }
  if (tid < SL) s_f[tid] = features[(size_t)bq * SL + tid];

  const float rscale = 0.03608439182435161f;  // 1/sqrt(768)
  for (int k = wave; k < SL; k += 8) {
    const uint2* kr = (const uint2*)(keyemb + ((size_t)(b * SL + k)) * HD);
    float part = 0.f;
#pragma unroll
    for (int j = 0; j < 3; ++j) {
      uint2 kv = kr[lane + 64 * j];  // 4 bf16 elems
      float4 h = hreg[j];
      part += bf_lo(kv.x) * h.x + bf_hi(kv.x) * h.y +
              bf_lo(kv.y) * h.z + bf_hi(kv.y) * h.w;
    }
#pragma unroll
    for (int off = 32; off; off >>= 1) part += __shfl_xor(part, off);
    if (lane == 0) s_p[k] = part * rscale;
  }
  __syncthreads();
  if (tid < SL) {
    float d = (pos[(size_t)bq * SL + tid] != 0) ? expf(s_p[tid]) : 0.f;
    s_p[tid] = d;
  }
  __syncthreads();
  if (tid < 64) {  // wave 0 tree-reduces the denominator
    float part = s_p[tid] + s_p[tid + 64];
#pragma unroll
    for (int off = 32; off; off >>= 1) part += __shfl_xor(part, off);
    if (tid == 0) s_sum = part + 1e-10f;
  }
  __syncthreads();

  // compact surviving (p, f) pairs
  int keep = 0;
  float pv = 0.f;
  int fv = 0;
  if (tid < SL) {
    pv = s_p[tid] / s_sum;
    fv = s_f[tid];
    keep = (pv != 0.f) && (fv != 0);
  }
  unsigned long long km = __ballot(keep);
  if (lane == 0 && wave < 2) s_cnt2[wave] = __popcll(km);
  __syncthreads();
  if (keep) {
    int rank = __popcll(km & ((1ull << lane) - 1ull)) + (wave == 1 ? s_cnt2[0] : 0);
    s_pc[rank] = pv;
    s_fc[rank] = fv;
  }
  if (tid == 0) s_m = s_cnt2[0] + s_cnt2[1];
  __syncthreads();
  int mm = s_m;

  // Gather: wave w handles entries e = 2w + 16*i and 2w+1 + 16*i.
  // Tail entries have pk == 0 (harmless row-0 load).
  int niter = (mm + 15) >> 4;
  float myp = 0.f;
  int myf = 0;
  {
    int el = 2 * wave + 16 * (lane >> 1) + (lane & 1);
    if (lane < 16 && el < mm) { myp = s_pc[el]; myf = s_fc[el]; }
  }
  float4 a0 = make_float4(0.f, 0.f, 0.f, 0.f);
  float4 a1 = a0, a2 = a0;
  for (int j = 0; j < niter; ++j) {
    float pk0 = __shfl(myp, 2 * j);
    int f0 = __shfl(myf, 2 * j);
    float pk1 = __shfl(myp, 2 * j + 1);
    int f1 = __shfl(myf, 2 * j + 1);
    const uint2* vr0 = (const uint2*)(wv16 + (size_t)f0 * HD);
    const uint2* vr1 = (const uint2*)(wv16 + (size_t)f1 * HD);
    uint2 x0 = vr0[lane], x1 = vr0[lane + 64], x2 = vr0[lane + 128];
    uint2 y0 = vr1[lane], y1 = vr1[lane + 64], y2 = vr1[lane + 128];
    a0.x += pk0 * bf_lo(x0.x); a0.y += pk0 * bf_hi(x0.x);
    a0.z += pk0 * bf_lo(x0.y); a0.w += pk0 * bf_hi(x0.y);
    a1.x += pk0 * bf_lo(x1.x); a1.y += pk0 * bf_hi(x1.x);
    a1.z += pk0 * bf_lo(x1.y); a1.w += pk0 * bf_hi(x1.y);
    a2.x += pk0 * bf_lo(x2.x); a2.y += pk0 * bf_hi(x2.x);
    a2.z += pk0 * bf_lo(x2.y); a2.w += pk0 * bf_hi(x2.y);
    a0.x += pk1 * bf_lo(y0.x); a0.y += pk1 * bf_hi(y0.x);
    a0.z += pk1 * bf_lo(y0.y); a0.w += pk1 * bf_hi(y0.y);
    a1.x += pk1 * bf_lo(y1.x); a1.y += pk1 * bf_hi(y1.x);
    a1.z += pk1 * bf_lo(y1.y); a1.w += pk1 * bf_hi(y1.y);
    a2.x += pk1 * bf_lo(y2.x); a2.y += pk1 * bf_hi(y2.x);
    a2.z += pk1 * bf_lo(y2.y); a2.w += pk1 * bf_hi(y2.y);
  }
  ((float4*)s_o[wave])[lane] = a0;
  ((float4*)s_o[wave])[lane + 64] = a1;
  ((float4*)s_o[wave])[lane + 128] = a2;
  __syncthreads();

  float* orow = o + (size_t)bq * HD;
  for (int h = tid; h < HD; h += 512) {
    float s = 0.f;
#pragma unroll
    for (int w = 0; w < 8; ++w) s += s_o[w][h];
    orow[h] = s;
  }
}

// Kernel 3: column mean with !=0 count. grid NB*6; 512 thr, 4 q-sub-slices.
__global__ __launch_bounds__(512) void k_avg(
    const float* __restrict__ o, float* __restrict__ avg) {
  int b = blockIdx.x / 6, c = blockIdx.x % 6;
  int tid = threadIdx.x;
  int hc = tid & 127;
  int h = c * 128 + hc;
  int sub = tid >> 7;  // 0..3, each sums 32 q's
  __shared__ float s_sum[4][128];
  __shared__ int s_cnt[4][128];
  float sum = 0.f;
  int cnt = 0;
#pragma unroll 8
  for (int q = sub * 32; q < (sub + 1) * 32; ++q) {
    float v = o[((size_t)(b * SL + q)) * HD + h];
    sum += v;
    cnt += (v != 0.f) ? 1 : 0;
  }
  s_sum[sub][hc] = sum;
  s_cnt[sub][hc] = cnt;
  __syncthreads();
  if (tid < 128) {
    float t = (s_sum[0][tid] + s_sum[1][tid]) + (s_sum[2][tid] + s_sum[3][tid]);
    int cc = (s_cnt[0][tid] + s_cnt[1][tid]) + (s_cnt[2][tid] + s_cnt[3][tid]);
    avg[(size_t)b * HD + c * 128 + tid] = t / (float)cc;  // IEEE inf/nan if cc==0
  }
}

// Kernel 4: logits = [pooled, avg] @ W_dense^T + b_dense
__global__ __launch_bounds__(192) void k_dense(
    const float* __restrict__ pooled,
    const float* __restrict__ avg,
    const float* __restrict__ W_dense,
    const float* __restrict__ b_dense,
    float* __restrict__ out) {
  int b = blockIdx.x;
  int tid = threadIdx.x;
  int n = tid >> 6, lane = tid & 63;
  float part = 0.f;
  for (int j = lane; j < HD; j += 64)
    part += pooled[(size_t)b * HD + j] * W_dense[(size_t)n * (2 * HD) + j];
  for (int j = lane; j < HD; j += 64)
    part += avg[(size_t)b * HD + j] * W_dense[(size_t)n * (2 * HD) + HD + j];
#pragma unroll
  for (int off = 32; off; off >>= 1) part += __shfl_xor(part, off);
  if (lane == 0) out[b * 3 + n] = part + b_dense[n];
}

extern "C" void kernel_launch(void* const* d_in, const int* in_sizes, int n_in,
                              void* d_out, int out_size, void* d_ws, size_t ws_size,
                              hipStream_t stream) {
  const float* seq     = (const float*)d_in[0];
  const float* pooled  = (const float*)d_in[1];
  const float* W_key   = (const float*)d_in[2];
  const float* W_val   = (const float*)d_in[3];
  const float* W_dense = (const float*)d_in[4];
  const float* b_dense = (const float*)d_in[5];
  const int* valid     = (const int*)d_in[6];
  const int* kvidx     = (const int*)d_in[7];
  const int* features  = (const int*)d_in[8];
  const int* pos       = (const int*)d_in[9];
  const int* aspect    = (const int*)d_in[10];
  float* out = (float*)d_out;

  float* hidden = (float*)d_ws;                               // [B,L,H] f32
  unsigned short* keyemb =
      (unsigned short*)(hidden + (size_t)NB * SL * HD);       // [B,L,H] bf16
  float* o = (float*)(keyemb + (size_t)NB * SL * HD);         // [B,L,H] f32
  float* avg = o + (size_t)NB * SL * HD;                      // [B,H]
  unsigned short* wv16 = (unsigned short*)(avg + (size_t)NB * HD);  // [16384,768] bf16

  k_prep<<<NB * SL + 3072, 256, 0, stream>>>(seq, W_key, W_val, valid, kvidx,
                                             aspect, hidden, keyemb, wv16);
  k_attend<<<NB * SL, 512, 0, stream>>>(hidden, keyemb, features, pos, wv16, o);
  k_avg<<<NB * 6, 512, 0, stream>>>(o, avg);
  k_dense<<<NB, 192, 0, stream>>>(pooled, avg, W_dense, b_dense, out);
}

// Round 9
// 49.046 us; speedup vs baseline: 1.4559x; 1.1626x over previous
//
#include <hip/hip_runtime.h>

#define NB 8
#define SL 128
#define HD 768

typedef float v2f __attribute__((ext_vector_type(2)));

__device__ __forceinline__ float bf_lo(unsigned int u) {
  return __uint_as_float(u << 16);
}
__device__ __forceinline__ float bf_hi(unsigned int u) {
  return __uint_as_float(u & 0xffff0000u);
}
__device__ __forceinline__ unsigned short f2bf(float x) {  // RNE
  unsigned int b = __float_as_uint(x);
  b += 0x7fffu + ((b >> 16) & 1u);
  return (unsigned short)(b >> 16);
}

// Kernel 1: blocks [0,1024): per-(b,i) pack -> hidden (f32) + keyemb (bf16).
// blocks [1024,4096): stream-convert W_val (16384x768 f32) -> fp8 e4m3.
__global__ __launch_bounds__(256) void k_prep(
    const float* __restrict__ seq,
    const float* __restrict__ W_key,
    const float* __restrict__ W_val,
    const int* __restrict__ valid,
    const int* __restrict__ kvidx,
    const int* __restrict__ aspect,
    float* __restrict__ hidden,
    unsigned short* __restrict__ keyemb,
    unsigned int* __restrict__ wv8) {
  int blk = blockIdx.x;
  int tid = threadIdx.x;

  if (blk >= NB * SL) {
    // W_val conversion: 3072 blocks x 256 thr x 4 x (float4 -> 4xfp8 uint)
    int cb = blk - NB * SL;
    const float4* src = (const float4*)W_val;
    int base = cb * 1024 + tid;
#pragma unroll
    for (int it = 0; it < 4; ++it) {
      float4 v = src[base + 256 * it];
      int w = __builtin_amdgcn_cvt_pk_fp8_f32(v.x, v.y, 0, false);
      w = __builtin_amdgcn_cvt_pk_fp8_f32(v.z, v.w, w, true);
      wv8[base + 256 * it] = (unsigned int)w;
    }
    return;
  }

  int b = blk & 7;
  int i = blk >> 3;
  int bq = b * SL + i;
  int lane = tid & 63, wv = tid >> 6;

  __shared__ int s_wcnt[4];
  __shared__ int s_src;

  int v = (tid < SL) ? (valid[b * SL + tid] != 0) : 0;
  unsigned long long m = __ballot(v);
  if (lane == 0) s_wcnt[wv] = __popcll(m);
  if (tid == 0) s_src = SL;  // sentinel
  __syncthreads();
  int count = s_wcnt[0] + s_wcnt[1];
  if (v) {
    int rank = __popcll(m & ((1ull << lane) - 1ull)) + (wv == 1 ? s_wcnt[0] : 0);
    if (rank == i) s_src = tid;
  }
  __syncthreads();
  int src = s_src;

  if (tid < HD / 4) {  // 192 threads, one float4 / ushort4 each
    float4 hv = make_float4(0.f, 0.f, 0.f, 0.f);
    if (i < count && src < SL) {
      float asp = (float)aspect[b * SL + i];
      const float4* srow = (const float4*)(seq + ((size_t)(b * SL + src)) * HD);
      float4 s = srow[tid];
      hv = make_float4(s.x * asp, s.y * asp, s.z * asp, s.w * asp);
    }
    ((float4*)(hidden + (size_t)bq * HD))[tid] = hv;

    int id = kvidx[b * SL + i];
    ushort4 kb = make_ushort4(0, 0, 0, 0);
    if (id != 0) {
      float4 kv = ((const float4*)(W_key + (size_t)id * HD))[tid];
      kb = make_ushort4(f2bf(kv.x), f2bf(kv.y), f2bf(kv.z), f2bf(kv.w));
    }
    ((ushort4*)(keyemb + (size_t)bq * HD))[tid] = kb;
  }
}

// Kernel 2 (fused): per (b,q) block, 512 threads / 8 waves.
// QK (bf16 keys, hidden in regs) -> masked softmax -> compacted gather of
// fp8 W_val rows (768 B/row), 2 entries/wave/iter.
// blockIdx % 8 == b pins each batch to one XCD (keyemb panel L2-local).
__global__ __launch_bounds__(512) void k_attend(
    const float* __restrict__ hidden,
    const unsigned short* __restrict__ keyemb,
    const int* __restrict__ features,
    const int* __restrict__ pos,
    const unsigned int* __restrict__ wv8,
    float* __restrict__ o) {
  int blk = blockIdx.x;
  int b = blk & 7;
  int q = blk >> 3;
  int bq = b * SL + q;
  int tid = threadIdx.x;
  int wave = tid >> 6, lane = tid & 63;

  __shared__ float s_p[SL];
  __shared__ int s_f[SL];
  __shared__ float s_pc[SL];
  __shared__ int s_fc[SL];
  __shared__ float s_o[8][HD];
  __shared__ float s_sum;
  __shared__ int s_cnt2[2];
  __shared__ int s_m;

  // hidden row into registers (each wave holds the full row, float4 layout)
  float4 hreg[3];
  {
    const float4* h4 = (const float4*)(hidden + (size_t)bq * HD);
#pragma unroll
    for (int j = 0; j < 3; ++j) hreg[j] = h4[lane + 64 * j];
  }
  if (tid < SL) s_f[tid] = features[(size_t)bq * SL + tid];

  const float rscale = 0.03608439182435161f;  // 1/sqrt(768)
  for (int k = wave; k < SL; k += 8) {
    const uint2* kr = (const uint2*)(keyemb + ((size_t)(b * SL + k)) * HD);
    float part = 0.f;
#pragma unroll
    for (int j = 0; j < 3; ++j) {
      uint2 kv = kr[lane + 64 * j];  // 4 bf16 elems
      float4 h = hreg[j];
      part += bf_lo(kv.x) * h.x + bf_hi(kv.x) * h.y +
              bf_lo(kv.y) * h.z + bf_hi(kv.y) * h.w;
    }
#pragma unroll
    for (int off = 32; off; off >>= 1) part += __shfl_xor(part, off);
    if (lane == 0) s_p[k] = part * rscale;
  }
  __syncthreads();
  if (tid < SL) {
    float d = (pos[(size_t)bq * SL + tid] != 0) ? expf(s_p[tid]) : 0.f;
    s_p[tid] = d;
  }
  __syncthreads();
  if (tid < 64) {  // wave 0 tree-reduces the denominator
    float part = s_p[tid] + s_p[tid + 64];
#pragma unroll
    for (int off = 32; off; off >>= 1) part += __shfl_xor(part, off);
    if (tid == 0) s_sum = part + 1e-10f;
  }
  __syncthreads();

  // compact surviving (p, f) pairs
  int keep = 0;
  float pv = 0.f;
  int fv = 0;
  if (tid < SL) {
    pv = s_p[tid] / s_sum;
    fv = s_f[tid];
    keep = (pv != 0.f) && (fv != 0);
  }
  unsigned long long km = __ballot(keep);
  if (lane == 0 && wave < 2) s_cnt2[wave] = __popcll(km);
  __syncthreads();
  if (keep) {
    int rank = __popcll(km & ((1ull << lane) - 1ull)) + (wave == 1 ? s_cnt2[0] : 0);
    s_pc[rank] = pv;
    s_fc[rank] = fv;
  }
  if (tid == 0) s_m = s_cnt2[0] + s_cnt2[1];
  __syncthreads();
  int mm = s_m;

  // Gather: wave w handles entries e = 2w + 16*i and 2w+1 + 16*i.
  // Tail entries have pk == 0 (harmless row-0 load).
  int niter = (mm + 15) >> 4;
  float myp = 0.f;
  int myf = 0;
  {
    int el = 2 * wave + 16 * (lane >> 1) + (lane & 1);
    if (lane < 16 && el < mm) { myp = s_pc[el]; myf = s_fc[el]; }
  }
  float4 a0 = make_float4(0.f, 0.f, 0.f, 0.f);
  float4 a1 = a0, a2 = a0;
  for (int j = 0; j < niter; ++j) {
    float pk0 = __shfl(myp, 2 * j);
    int f0 = __shfl(myf, 2 * j);
    float pk1 = __shfl(myp, 2 * j + 1);
    int f1 = __shfl(myf, 2 * j + 1);
    const unsigned int* vr0 = wv8 + (size_t)f0 * (HD / 4);
    const unsigned int* vr1 = wv8 + (size_t)f1 * (HD / 4);
    unsigned int x0 = vr0[lane], x1 = vr0[lane + 64], x2 = vr0[lane + 128];
    unsigned int y0 = vr1[lane], y1 = vr1[lane + 64], y2 = vr1[lane + 128];
    v2f p0, p1;
    p0 = __builtin_amdgcn_cvt_pk_f32_fp8(x0, false);
    p1 = __builtin_amdgcn_cvt_pk_f32_fp8(x0, true);
    a0.x += pk0 * p0.x; a0.y += pk0 * p0.y; a0.z += pk0 * p1.x; a0.w += pk0 * p1.y;
    p0 = __builtin_amdgcn_cvt_pk_f32_fp8(x1, false);
    p1 = __builtin_amdgcn_cvt_pk_f32_fp8(x1, true);
    a1.x += pk0 * p0.x; a1.y += pk0 * p0.y; a1.z += pk0 * p1.x; a1.w += pk0 * p1.y;
    p0 = __builtin_amdgcn_cvt_pk_f32_fp8(x2, false);
    p1 = __builtin_amdgcn_cvt_pk_f32_fp8(x2, true);
    a2.x += pk0 * p0.x; a2.y += pk0 * p0.y; a2.z += pk0 * p1.x; a2.w += pk0 * p1.y;
    p0 = __builtin_amdgcn_cvt_pk_f32_fp8(y0, false);
    p1 = __builtin_amdgcn_cvt_pk_f32_fp8(y0, true);
    a0.x += pk1 * p0.x; a0.y += pk1 * p0.y; a0.z += pk1 * p1.x; a0.w += pk1 * p1.y;
    p0 = __builtin_amdgcn_cvt_pk_f32_fp8(y1, false);
    p1 = __builtin_amdgcn_cvt_pk_f32_fp8(y1, true);
    a1.x += pk1 * p0.x; a1.y += pk1 * p0.y; a1.z += pk1 * p1.x; a1.w += pk1 * p1.y;
    p0 = __builtin_amdgcn_cvt_pk_f32_fp8(y2, false);
    p1 = __builtin_amdgcn_cvt_pk_f32_fp8(y2, true);
    a2.x += pk1 * p0.x; a2.y += pk1 * p0.y; a2.z += pk1 * p1.x; a2.w += pk1 * p1.y;
  }
  ((float4*)s_o[wave])[lane] = a0;
  ((float4*)s_o[wave])[lane + 64] = a1;
  ((float4*)s_o[wave])[lane + 128] = a2;
  __syncthreads();

  float* orow = o + (size_t)bq * HD;
  for (int h = tid; h < HD; h += 512) {
    float s = 0.f;
#pragma unroll
    for (int w = 0; w < 8; ++w) s += s_o[w][h];
    orow[h] = s;
  }
}

// Kernel 3: column mean with !=0 count. grid NB*6; 512 thr, 4 q-sub-slices.
__global__ __launch_bounds__(512) void k_avg(
    const float* __restrict__ o, float* __restrict__ avg) {
  int b = blockIdx.x / 6, c = blockIdx.x % 6;
  int tid = threadIdx.x;
  int hc = tid & 127;
  int h = c * 128 + hc;
  int sub = tid >> 7;  // 0..3, each sums 32 q's
  __shared__ float s_sum[4][128];
  __shared__ int s_cnt[4][128];
  float sum = 0.f;
  int cnt = 0;
#pragma unroll 8
  for (int q = sub * 32; q < (sub + 1) * 32; ++q) {
    float v = o[((size_t)(b * SL + q)) * HD + h];
    sum += v;
    cnt += (v != 0.f) ? 1 : 0;
  }
  s_sum[sub][hc] = sum;
  s_cnt[sub][hc] = cnt;
  __syncthreads();
  if (tid < 128) {
    float t = (s_sum[0][tid] + s_sum[1][tid]) + (s_sum[2][tid] + s_sum[3][tid]);
    int cc = (s_cnt[0][tid] + s_cnt[1][tid]) + (s_cnt[2][tid] + s_cnt[3][tid]);
    avg[(size_t)b * HD + c * 128 + tid] = t / (float)cc;  // IEEE inf/nan if cc==0
  }
}

// Kernel 4: logits = [pooled, avg] @ W_dense^T + b_dense
__global__ __launch_bounds__(192) void k_dense(
    const float* __restrict__ pooled,
    const float* __restrict__ avg,
    const float* __restrict__ W_dense,
    const float* __restrict__ b_dense,
    float* __restrict__ out) {
  int b = blockIdx.x;
  int tid = threadIdx.x;
  int n = tid >> 6, lane = tid & 63;
  float part = 0.f;
  for (int j = lane; j < HD; j += 64)
    part += pooled[(size_t)b * HD + j] * W_dense[(size_t)n * (2 * HD) + j];
  for (int j = lane; j < HD; j += 64)
    part += avg[(size_t)b * HD + j] * W_dense[(size_t)n * (2 * HD) + HD + j];
#pragma unroll
  for (int off = 32; off; off >>= 1) part += __shfl_xor(part, off);
  if (lane == 0) out[b * 3 + n] = part + b_dense[n];
}

extern "C" void kernel_launch(void* const* d_in, const int* in_sizes, int n_in,
                              void* d_out, int out_size, void* d_ws, size_t ws_size,
                              hipStream_t stream) {
  const float* seq     = (const float*)d_in[0];
  const float* pooled  = (const float*)d_in[1];
  const float* W_key   = (const float*)d_in[2];
  const float* W_val   = (const float*)d_in[3];
  const float* W_dense = (const float*)d_in[4];
  const float* b_dense = (const float*)d_in[5];
  const int* valid     = (const int*)d_in[6];
  const int* kvidx     = (const int*)d_in[7];
  const int* features  = (const int*)d_in[8];
  const int* pos       = (const int*)d_in[9];
  const int* aspect    = (const int*)d_in[10];
  float* out = (float*)d_out;

  float* hidden = (float*)d_ws;                               // [B,L,H] f32
  unsigned short* keyemb =
      (unsigned short*)(hidden + (size_t)NB * SL * HD);       // [B,L,H] bf16
  float* o = (float*)(keyemb + (size_t)NB * SL * HD);         // [B,L,H] f32
  float* avg = o + (size_t)NB * SL * HD;                      // [B,H]
  unsigned int* wv8 = (unsigned int*)(avg + (size_t)NB * HD); // [16384,768] fp8

  k_prep<<<NB * SL + 3072, 256, 0, stream>>>(seq, W_key, W_val, valid, kvidx,
                                             aspect, hidden, keyemb, wv8);
  k_attend<<<NB * SL, 512, 0, stream>>>(hidden, keyemb, features, pos, wv8, o);
  k_avg<<<NB * 6, 512, 0, stream>>>(o, avg);
  k_dense<<<NB, 192, 0, stream>>>(pooled, avg, W_dense, b_dense, out);
}